// Round 1
// baseline (168.943 us; speedup 1.0000x reference)
//
#include <hip/hip_runtime.h>

// Problem constants
#define T_STEPS 128
#define BATCH   64
#define DIMX    32
#define S_SUP   1024
#define NROW    8192          // T*B
#define OUT_H_SZ   (T_STEPS*BATCH*4)      // 32768
#define OUT_RBF_SZ (NROW*S_SUP)           // 8388608

__device__ __forceinline__ float rcp_fast(float x) { return __builtin_amdgcn_rcpf(x); }

// ---------------------------------------------------------------------------
// Kernel 1: pre[row][g][w] = b_g[w] + p_g[w] + sum_d x[row][d] * W_g[w][d]
// row = t*64+b; layout float4-friendly: ((row*4+g)*4+w)
// ---------------------------------------------------------------------------
__global__ __launch_bounds__(256) void pre_kernel(
    const float* __restrict__ x,
    const float* __restrict__ Wf, const float* __restrict__ bf,
    const float* __restrict__ Wi, const float* __restrict__ bi,
    const float* __restrict__ Wu, const float* __restrict__ bu,
    const float* __restrict__ Wo, const float* __restrict__ bo,
    const float* __restrict__ pf, const float* __restrict__ pi,
    const float* __restrict__ pu, const float* __restrict__ po,
    float* __restrict__ pre)
{
    const int tid = threadIdx.x;
    const int rl  = tid >> 4;          // 16 rows per block
    const int gw  = tid & 15;
    const int g   = gw >> 2, w = gw & 3;
    const int row = blockIdx.x * 16 + rl;

    __shared__ float xs[16 * DIMX];
    if (tid < 128) {
        ((float4*)xs)[tid] = ((const float4*)(x + (size_t)blockIdx.x * 16 * DIMX))[tid];
    }
    __syncthreads();

    const float* W  = (g == 0) ? Wf : (g == 1) ? Wi : (g == 2) ? Wu : Wo;
    const float* bb = (g == 0) ? bf : (g == 1) ? bi : (g == 2) ? bu : bo;
    const float* pp = (g == 0) ? pf : (g == 1) ? pi : (g == 2) ? pu : po;

    float acc = bb[w] + pp[w];
    const float* Wr = W + w * 36;      // row stride D+H = 36
    const float* xr = xs + rl * DIMX;
#pragma unroll
    for (int d = 0; d < DIMX; d++) acc += xr[d] * Wr[d];

    pre[(row * 4 + g) * 4 + w] = acc;
}

// ---------------------------------------------------------------------------
// Kernel 2 (fused): block 0 = sequential LSTM, blocks 1..512 = rbf+qk tiles
// ---------------------------------------------------------------------------
template <bool USE_PRE>
__global__ __launch_bounds__(256) void fused_kernel(
    const float* __restrict__ x,  const float* __restrict__ sv,
    const float* __restrict__ Wf, const float* __restrict__ bf,
    const float* __restrict__ Wi, const float* __restrict__ bi,
    const float* __restrict__ Wu, const float* __restrict__ bu,
    const float* __restrict__ Wo, const float* __restrict__ bo,
    const float* __restrict__ pf, const float* __restrict__ pi,
    const float* __restrict__ pu, const float* __restrict__ po,
    const float* __restrict__ qkp, const float* __restrict__ pre,
    float* __restrict__ out_h, float* __restrict__ out_rbf, float* __restrict__ out_qk)
{
    __shared__ float xs[BATCH * DIMX];   // rbf path: 64-row x tile (8 KB)
    __shared__ float xn2[BATCH];
    const int tid = threadIdx.x;

    if (blockIdx.x == 0) {
        // ================= LSTM: thread = (b, g); 4 wires in-lane ==========
        const int b = tid >> 2, g = tid & 3;
        const float* W = (g == 0) ? Wf : (g == 1) ? Wi : (g == 2) ? Wu : Wo;

        float Wh[4][4];                      // hidden part W[w][32+j]
#pragma unroll
        for (int w = 0; w < 4; w++)
#pragma unroll
            for (int j = 0; j < 4; j++) Wh[w][j] = W[w * 36 + 32 + j];

        // per-lane activation constants: g==2 -> tanh = 2*sigmoid(2x)-1
        const float kexp = (g == 2) ? -2.f : -1.f;
        const float Aa   = (g == 2) ?  2.f :  1.f;
        const float Bb   = (g == 2) ? -1.f :  0.f;

        float h0 = 0.f, h1 = 0.f, h2 = 0.f, h3 = 0.f;
        float c0 = 0.f, c1 = 0.f, c2 = 0.f, c3 = 0.f;
        const int lane = tid & 63;
        const int qb   = lane & ~3;          // quad base (fixed b, g=0..3)
        const int base = b * 4 + g;          // float4 index inside one t slab (256/t)
        const float4* prep = (const float4*)pre;

        float4 buf0, buf1, buf2, buf3;       // 4-deep prefetch of pre
        if constexpr (USE_PRE) {
            buf0 = prep[base];
            buf1 = prep[base + 256];
            buf2 = prep[base + 512];
            buf3 = prep[base + 768];
        }
        float  bbp[4];
        float4 Wxv[4][8];                    // fallback path only
        if constexpr (!USE_PRE) {
            const float* bptr = (g == 0) ? bf : (g == 1) ? bi : (g == 2) ? bu : bo;
            const float* pptr = (g == 0) ? pf : (g == 1) ? pi : (g == 2) ? pu : po;
#pragma unroll
            for (int w = 0; w < 4; w++) {
                bbp[w] = bptr[w] + pptr[w];
#pragma unroll
                for (int k = 0; k < 8; k++) Wxv[w][k] = ((const float4*)(W + w * 36))[k];
            }
        }

#pragma unroll 4
        for (int t = 0; t < T_STEPS; t++) {
            float a0, a1, a2, a3;
            if constexpr (USE_PRE) {
                float4 cur = buf0;
                buf0 = buf1; buf1 = buf2; buf2 = buf3;
                if (t < T_STEPS - 4) buf3 = prep[base + (t + 4) * 256];
                a0 = cur.x; a1 = cur.y; a2 = cur.z; a3 = cur.w;
            } else {
                const float4* xr = (const float4*)(x + (size_t)(t * BATCH + b) * DIMX);
                float4 xv[8];
#pragma unroll
                for (int k = 0; k < 8; k++) xv[k] = xr[k];
                a0 = bbp[0]; a1 = bbp[1]; a2 = bbp[2]; a3 = bbp[3];
#pragma unroll
                for (int k = 0; k < 8; k++) {
                    a0 += xv[k].x * Wxv[0][k].x + xv[k].y * Wxv[0][k].y + xv[k].z * Wxv[0][k].z + xv[k].w * Wxv[0][k].w;
                    a1 += xv[k].x * Wxv[1][k].x + xv[k].y * Wxv[1][k].y + xv[k].z * Wxv[1][k].z + xv[k].w * Wxv[1][k].w;
                    a2 += xv[k].x * Wxv[2][k].x + xv[k].y * Wxv[2][k].y + xv[k].z * Wxv[2][k].z + xv[k].w * Wxv[2][k].w;
                    a3 += xv[k].x * Wxv[3][k].x + xv[k].y * Wxv[3][k].y + xv[k].z * Wxv[3][k].z + xv[k].w * Wxv[3][k].w;
                }
            }
            // hidden contribution
            a0 += h0 * Wh[0][0] + h1 * Wh[0][1] + h2 * Wh[0][2] + h3 * Wh[0][3];
            a1 += h0 * Wh[1][0] + h1 * Wh[1][1] + h2 * Wh[1][2] + h3 * Wh[1][3];
            a2 += h0 * Wh[2][0] + h1 * Wh[2][1] + h2 * Wh[2][2] + h3 * Wh[2][3];
            a3 += h0 * Wh[3][0] + h1 * Wh[3][1] + h2 * Wh[3][2] + h3 * Wh[3][3];

            // closed-form circuit: C_w = cos(angle_w); PERM_WRAP-conjugated Z:
            float C0 = __cosf(a0), C1 = __cosf(a1), C2 = __cosf(a2), C3 = __cosf(a3);
            float t23 = C2 * C3;
            float m01 = C0 * C1;
            float r0 = C1 * t23;     // <Z0> = C1 C2 C3
            float r1 = m01;          // <Z1> = C0 C1
            float r2 = m01 * C2;     // <Z2> = C0 C1 C2
            float r3 = m01 * t23;    // <Z3> = C0 C1 C2 C3

            // activation (sigmoid, or tanh for g==2), branch-free per-lane consts
            float o0 = Aa * rcp_fast(1.f + __expf(r0 * kexp)) + Bb;
            float o1 = Aa * rcp_fast(1.f + __expf(r1 * kexp)) + Bb;
            float o2 = Aa * rcp_fast(1.f + __expf(r2 * kexp)) + Bb;
            float o3 = Aa * rcp_fast(1.f + __expf(r3 * kexp)) + Bb;

            // gather f/i/u/o vectors from quad lanes (g = 0,1,2,3)
            float f0 = __shfl(o0, qb),     f1 = __shfl(o1, qb),     f2 = __shfl(o2, qb),     f3 = __shfl(o3, qb);
            float i0 = __shfl(o0, qb + 1), i1 = __shfl(o1, qb + 1), i2 = __shfl(o2, qb + 1), i3 = __shfl(o3, qb + 1);
            float u0 = __shfl(o0, qb + 2), u1 = __shfl(o1, qb + 2), u2 = __shfl(o2, qb + 2), u3 = __shfl(o3, qb + 2);
            float z0 = __shfl(o0, qb + 3), z1 = __shfl(o1, qb + 3), z2 = __shfl(o2, qb + 3), z3 = __shfl(o3, qb + 3);

            c0 = f0 * c0 + i0 * u0;
            c1 = f1 * c1 + i1 * u1;
            c2 = f2 * c2 + i2 * u2;
            c3 = f3 * c3 + i3 * u3;

            float t0 = 2.f * rcp_fast(1.f + __expf(-2.f * c0)) - 1.f;
            float t1 = 2.f * rcp_fast(1.f + __expf(-2.f * c1)) - 1.f;
            float t2 = 2.f * rcp_fast(1.f + __expf(-2.f * c2)) - 1.f;
            float t3 = 2.f * rcp_fast(1.f + __expf(-2.f * c3)) - 1.f;
            h0 = z0 * t0; h1 = z1 * t1; h2 = z2 * t2; h3 = z3 * t3;

            if (g == 0) {
                float4 hv; hv.x = h0; hv.y = h1; hv.z = h2; hv.w = h3;
                ((float4*)out_h)[t * BATCH + b] = hv;
            }
        }
    } else {
        // ================= rbf + qk tile: 64 n x 256 s =====================
        const int bid = blockIdx.x - 1;
        const int n0  = (bid >> 2) * BATCH;
        const int s0  = (bid & 3) * 256;

        float4* xs4 = (float4*)xs;
        const float4* xg = (const float4*)(x + (size_t)n0 * DIMX);
        xs4[tid]       = xg[tid];
        xs4[tid + 256] = xg[tid + 256];
        __syncthreads();

        if (tid < BATCH) {                   // per-row |x|^2
            const float* xr = xs + tid * DIMX;
            float acc = 0.f;
#pragma unroll
            for (int d = 0; d < DIMX; d++) acc += xr[d] * xr[d];
            xn2[tid] = acc;
        }

        const int s = s0 + tid;              // this thread's support vector
        float4 svv[8];
        const float4* svg = (const float4*)(sv + (size_t)s * DIMX);
#pragma unroll
        for (int k = 0; k < 8; k++) svv[k] = svg[k];
        float sn2 = 0.f;
#pragma unroll
        for (int k = 0; k < 8; k++)
            sn2 += svv[k].x * svv[k].x + svv[k].y * svv[k].y + svv[k].z * svv[k].z + svv[k].w * svv[k].w;

        // qk s-side: B_w = sv_w/2 + qk_w   (PERM_LINE drops out of sx@sy.T)
        const float B0 = 0.5f * svv[0].x + qkp[0];
        const float B1 = 0.5f * svv[0].y + qkp[1];
        const float B2 = 0.5f * svv[0].z + qkp[2];
        const float B3 = 0.5f * svv[0].w + qkp[3];
        __syncthreads();

#pragma unroll 4
        for (int n = 0; n < BATCH; n++) {
            const float4* xr4 = (const float4*)(xs + n * DIMX);   // broadcast reads
            float4 xv0 = xr4[0];
            float dot = xv0.x * svv[0].x + xv0.y * svv[0].y + xv0.z * svv[0].z + xv0.w * svv[0].w;
#pragma unroll
            for (int k = 1; k < 8; k++) {
                float4 xv = xr4[k];
                dot += xv.x * svv[k].x + xv.y * svv[k].y + xv.z * svv[k].z + xv.w * svv[k].w;
            }
            float dist = xn2[n] + sn2 - 2.f * dot;
            float rb   = __expf(-dist);

            float qv = __cosf(0.5f * xv0.x + B0) * __cosf(0.5f * xv0.y + B1)
                     * __cosf(0.5f * xv0.z + B2) * __cosf(0.5f * xv0.w + B3);
            qv = fabsf(qv);

            const int row = n0 + n;
            out_rbf[(size_t)row * S_SUP + s] = rb;
            out_qk [(size_t)row * S_SUP + s] = qv;
        }
    }
}

// ---------------------------------------------------------------------------
extern "C" void kernel_launch(void* const* d_in, const int* in_sizes, int n_in,
                              void* d_out, int out_size, void* d_ws, size_t ws_size,
                              hipStream_t stream)
{
    const float* x   = (const float*)d_in[0];
    const float* sv  = (const float*)d_in[1];
    const float* Wf  = (const float*)d_in[2];
    const float* bf  = (const float*)d_in[3];
    const float* Wi  = (const float*)d_in[4];
    const float* bi  = (const float*)d_in[5];
    const float* Wu  = (const float*)d_in[6];
    const float* bu  = (const float*)d_in[7];
    const float* Wo  = (const float*)d_in[8];
    const float* bo  = (const float*)d_in[9];
    const float* pf  = (const float*)d_in[10];
    const float* pi  = (const float*)d_in[11];
    const float* pu  = (const float*)d_in[12];
    const float* po  = (const float*)d_in[13];
    const float* qkp = (const float*)d_in[14];

    float* out     = (float*)d_out;
    float* out_h   = out;
    float* out_rbf = out + OUT_H_SZ;
    float* out_qk  = out + OUT_H_SZ + OUT_RBF_SZ;

    const size_t pre_bytes = (size_t)NROW * 16 * sizeof(float);   // 512 KB
    const bool use_pre = (ws_size >= pre_bytes);
    float* pre = (float*)d_ws;

    if (use_pre) {
        pre_kernel<<<NROW / 16, 256, 0, stream>>>(x, Wf, bf, Wi, bi, Wu, bu, Wo, bo,
                                                  pf, pi, pu, po, pre);
        fused_kernel<true><<<1 + 512, 256, 0, stream>>>(
            x, sv, Wf, bf, Wi, bi, Wu, bu, Wo, bo, pf, pi, pu, po, qkp, pre,
            out_h, out_rbf, out_qk);
    } else {
        fused_kernel<false><<<1 + 512, 256, 0, stream>>>(
            x, sv, Wf, bf, Wi, bi, Wu, bu, Wo, bo, pf, pi, pu, po, qkp, (const float*)nullptr,
            out_h, out_rbf, out_qk);
    }
}

// Round 2
// 151.463 us; speedup vs baseline: 1.1154x; 1.1154x over previous
//
#include <hip/hip_runtime.h>

// Problem constants
#define T_STEPS 128
#define BATCH   64
#define DIMX    32
#define S_SUP   1024
#define NROW    8192          // T*B
#define OUT_H_SZ   (T_STEPS*BATCH*4)      // 32768
#define OUT_RBF_SZ (NROW*S_SUP)           // 8388608

__device__ __forceinline__ float rcp_fast(float x) { return __builtin_amdgcn_rcpf(x); }

// Intra-quad broadcast via DPP quad_perm (VALU latency ~2-4 cy, vs ~120 cy ds_bpermute)
template<int K>
__device__ __forceinline__ float quad_bcast(float v) {
    constexpr int ctrl = K * 0x55;   // K | K<<2 | K<<4 | K<<6
    return __builtin_bit_cast(float,
        __builtin_amdgcn_mov_dpp(__builtin_bit_cast(int, v), ctrl, 0xF, 0xF, true));
}

// ---------------------------------------------------------------------------
// Kernel 1: pre[row][g][w] = b_g[w] + p_g[w] + sum_d x[row][d] * W_g[w][d]
// row = t*64+b; layout float4-friendly: ((row*4+g)*4+w)
// ---------------------------------------------------------------------------
__global__ __launch_bounds__(256) void pre_kernel(
    const float* __restrict__ x,
    const float* __restrict__ Wf, const float* __restrict__ bf,
    const float* __restrict__ Wi, const float* __restrict__ bi,
    const float* __restrict__ Wu, const float* __restrict__ bu,
    const float* __restrict__ Wo, const float* __restrict__ bo,
    const float* __restrict__ pf, const float* __restrict__ pi,
    const float* __restrict__ pu, const float* __restrict__ po,
    float* __restrict__ pre)
{
    const int tid = threadIdx.x;
    const int rl  = tid >> 4;          // 16 rows per block
    const int gw  = tid & 15;
    const int g   = gw >> 2, w = gw & 3;
    const int row = blockIdx.x * 16 + rl;

    __shared__ float xs[16 * DIMX];
    if (tid < 128) {
        ((float4*)xs)[tid] = ((const float4*)(x + (size_t)blockIdx.x * 16 * DIMX))[tid];
    }
    __syncthreads();

    const float* W  = (g == 0) ? Wf : (g == 1) ? Wi : (g == 2) ? Wu : Wo;
    const float* bb = (g == 0) ? bf : (g == 1) ? bi : (g == 2) ? bu : bo;
    const float* pp = (g == 0) ? pf : (g == 1) ? pi : (g == 2) ? pu : po;

    float acc = bb[w] + pp[w];
    const float* Wr = W + w * 36;      // row stride D+H = 36
    const float* xr = xs + rl * DIMX;
#pragma unroll
    for (int d = 0; d < DIMX; d++) acc += xr[d] * Wr[d];

    pre[(row * 4 + g) * 4 + w] = acc;
}

// ---------------------------------------------------------------------------
// Kernel 2 (fused): block 0 = sequential LSTM, blocks 1..512 = rbf+qk tiles
// ---------------------------------------------------------------------------
template <bool USE_PRE>
__global__ __launch_bounds__(256) void fused_kernel(
    const float* __restrict__ x,  const float* __restrict__ sv,
    const float* __restrict__ Wf, const float* __restrict__ bf,
    const float* __restrict__ Wi, const float* __restrict__ bi,
    const float* __restrict__ Wu, const float* __restrict__ bu,
    const float* __restrict__ Wo, const float* __restrict__ bo,
    const float* __restrict__ pf, const float* __restrict__ pi,
    const float* __restrict__ pu, const float* __restrict__ po,
    const float* __restrict__ qkp, const float* __restrict__ pre,
    float* __restrict__ out_h, float* __restrict__ out_rbf, float* __restrict__ out_qk)
{
    __shared__ float xs[BATCH * DIMX];   // rbf path: 64-row x tile (8 KB)
    __shared__ float xn2[BATCH];
    const int tid = threadIdx.x;

    if (blockIdx.x == 0) {
        // ================= LSTM: thread = (b, g); 4 wires in-lane ==========
        const int b = tid >> 2, g = tid & 3;
        const float* W = (g == 0) ? Wf : (g == 1) ? Wi : (g == 2) ? Wu : Wo;

        float Wh[4][4];                      // hidden part W[w][32+j]
#pragma unroll
        for (int w = 0; w < 4; w++)
#pragma unroll
            for (int j = 0; j < 4; j++) Wh[w][j] = W[w * 36 + 32 + j];

        // per-lane activation constants: g==2 -> tanh = 2*sigmoid(2x)-1
        const float kexp = (g == 2) ? -2.f : -1.f;
        const float Aa   = (g == 2) ?  2.f :  1.f;
        const float Bb   = (g == 2) ? -1.f :  0.f;

        float h0 = 0.f, h1 = 0.f, h2 = 0.f, h3 = 0.f;
        float c0 = 0.f, c1 = 0.f, c2 = 0.f, c3 = 0.f;
        const int base = b * 4 + g;          // float4 index inside one t slab (256/t)
        const float4* prep = (const float4*)pre;

        // 8-deep cyclic prefetch: slot consumed at t was loaded at t-8 -> 8
        // loads in flight, per-step wait ~latency/8, hidden under compute.
        constexpr int PF = 8;
        float4 buf[PF];
        if constexpr (USE_PRE) {
#pragma unroll
            for (int k = 0; k < PF; k++) buf[k] = prep[base + k * 256];
        }

        float  bbp[4];
        float4 Wxv[4][8];                    // fallback path only
        if constexpr (!USE_PRE) {
            const float* bptr = (g == 0) ? bf : (g == 1) ? bi : (g == 2) ? bu : bo;
            const float* pptr = (g == 0) ? pf : (g == 1) ? pi : (g == 2) ? pu : po;
#pragma unroll
            for (int w = 0; w < 4; w++) {
                bbp[w] = bptr[w] + pptr[w];
#pragma unroll
                for (int k = 0; k < 8; k++) Wxv[w][k] = ((const float4*)(W + w * 36))[k];
            }
        }

#pragma unroll 8
        for (int t = 0; t < T_STEPS; t++) {
            float a0, a1, a2, a3;
            if constexpr (USE_PRE) {
                float4 cur = buf[t & (PF - 1)];
                if (t + PF < T_STEPS) buf[t & (PF - 1)] = prep[base + (t + PF) * 256];
                a0 = cur.x; a1 = cur.y; a2 = cur.z; a3 = cur.w;
            } else {
                const float4* xr = (const float4*)(x + (size_t)(t * BATCH + b) * DIMX);
                float4 xv[8];
#pragma unroll
                for (int k = 0; k < 8; k++) xv[k] = xr[k];
                a0 = bbp[0]; a1 = bbp[1]; a2 = bbp[2]; a3 = bbp[3];
#pragma unroll
                for (int k = 0; k < 8; k++) {
                    a0 += xv[k].x * Wxv[0][k].x + xv[k].y * Wxv[0][k].y + xv[k].z * Wxv[0][k].z + xv[k].w * Wxv[0][k].w;
                    a1 += xv[k].x * Wxv[1][k].x + xv[k].y * Wxv[1][k].y + xv[k].z * Wxv[1][k].z + xv[k].w * Wxv[1][k].w;
                    a2 += xv[k].x * Wxv[2][k].x + xv[k].y * Wxv[2][k].y + xv[k].z * Wxv[2][k].z + xv[k].w * Wxv[2][k].w;
                    a3 += xv[k].x * Wxv[3][k].x + xv[k].y * Wxv[3][k].y + xv[k].z * Wxv[3][k].z + xv[k].w * Wxv[3][k].w;
                }
            }
            // hidden contribution
            a0 += h0 * Wh[0][0] + h1 * Wh[0][1] + h2 * Wh[0][2] + h3 * Wh[0][3];
            a1 += h0 * Wh[1][0] + h1 * Wh[1][1] + h2 * Wh[1][2] + h3 * Wh[1][3];
            a2 += h0 * Wh[2][0] + h1 * Wh[2][1] + h2 * Wh[2][2] + h3 * Wh[2][3];
            a3 += h0 * Wh[3][0] + h1 * Wh[3][1] + h2 * Wh[3][2] + h3 * Wh[3][3];

            // closed-form circuit: C_w = cos(angle_w); PERM_WRAP-conjugated Z:
            float C0 = __cosf(a0), C1 = __cosf(a1), C2 = __cosf(a2), C3 = __cosf(a3);
            float t23 = C2 * C3;
            float m01 = C0 * C1;
            float r0 = C1 * t23;     // <Z0> = C1 C2 C3
            float r1 = m01;          // <Z1> = C0 C1
            float r2 = m01 * C2;     // <Z2> = C0 C1 C2
            float r3 = m01 * t23;    // <Z3> = C0 C1 C2 C3

            // activation (sigmoid, or tanh for g==2), branch-free per-lane consts
            float o0 = Aa * rcp_fast(1.f + __expf(r0 * kexp)) + Bb;
            float o1 = Aa * rcp_fast(1.f + __expf(r1 * kexp)) + Bb;
            float o2 = Aa * rcp_fast(1.f + __expf(r2 * kexp)) + Bb;
            float o3 = Aa * rcp_fast(1.f + __expf(r3 * kexp)) + Bb;

            // gather f/i/u/o vectors from quad lanes (g = 0,1,2,3) via DPP
            float f0 = quad_bcast<0>(o0), f1 = quad_bcast<0>(o1), f2 = quad_bcast<0>(o2), f3 = quad_bcast<0>(o3);
            float i0 = quad_bcast<1>(o0), i1 = quad_bcast<1>(o1), i2 = quad_bcast<1>(o2), i3 = quad_bcast<1>(o3);
            float u0 = quad_bcast<2>(o0), u1 = quad_bcast<2>(o1), u2 = quad_bcast<2>(o2), u3 = quad_bcast<2>(o3);
            float z0 = quad_bcast<3>(o0), z1 = quad_bcast<3>(o1), z2 = quad_bcast<3>(o2), z3 = quad_bcast<3>(o3);

            c0 = f0 * c0 + i0 * u0;
            c1 = f1 * c1 + i1 * u1;
            c2 = f2 * c2 + i2 * u2;
            c3 = f3 * c3 + i3 * u3;

            float t0 = 2.f * rcp_fast(1.f + __expf(-2.f * c0)) - 1.f;
            float t1 = 2.f * rcp_fast(1.f + __expf(-2.f * c1)) - 1.f;
            float t2 = 2.f * rcp_fast(1.f + __expf(-2.f * c2)) - 1.f;
            float t3 = 2.f * rcp_fast(1.f + __expf(-2.f * c3)) - 1.f;
            h0 = z0 * t0; h1 = z1 * t1; h2 = z2 * t2; h3 = z3 * t3;

            if (g == 0) {
                float4 hv; hv.x = h0; hv.y = h1; hv.z = h2; hv.w = h3;
                ((float4*)out_h)[t * BATCH + b] = hv;
            }
        }
    } else {
        // ================= rbf + qk tile: 64 n x 256 s =====================
        const int bid = blockIdx.x - 1;
        const int n0  = (bid >> 2) * BATCH;
        const int s0  = (bid & 3) * 256;

        float4* xs4 = (float4*)xs;
        const float4* xg = (const float4*)(x + (size_t)n0 * DIMX);
        xs4[tid]       = xg[tid];
        xs4[tid + 256] = xg[tid + 256];
        __syncthreads();

        if (tid < BATCH) {                   // per-row |x|^2
            const float* xr = xs + tid * DIMX;
            float acc = 0.f;
#pragma unroll
            for (int d = 0; d < DIMX; d++) acc += xr[d] * xr[d];
            xn2[tid] = acc;
        }

        const int s = s0 + tid;              // this thread's support vector
        float4 svv[8];
        const float4* svg = (const float4*)(sv + (size_t)s * DIMX);
#pragma unroll
        for (int k = 0; k < 8; k++) svv[k] = svg[k];
        float sn2 = 0.f;
#pragma unroll
        for (int k = 0; k < 8; k++)
            sn2 += svv[k].x * svv[k].x + svv[k].y * svv[k].y + svv[k].z * svv[k].z + svv[k].w * svv[k].w;

        // qk s-side: B_w = sv_w/2 + qk_w   (PERM_LINE drops out of sx@sy.T)
        const float B0 = 0.5f * svv[0].x + qkp[0];
        const float B1 = 0.5f * svv[0].y + qkp[1];
        const float B2 = 0.5f * svv[0].z + qkp[2];
        const float B3 = 0.5f * svv[0].w + qkp[3];
        __syncthreads();

#pragma unroll 4
        for (int n = 0; n < BATCH; n++) {
            const float4* xr4 = (const float4*)(xs + n * DIMX);   // broadcast reads
            float4 xv0 = xr4[0];
            float dot = xv0.x * svv[0].x + xv0.y * svv[0].y + xv0.z * svv[0].z + xv0.w * svv[0].w;
#pragma unroll
            for (int k = 1; k < 8; k++) {
                float4 xv = xr4[k];
                dot += xv.x * svv[k].x + xv.y * svv[k].y + xv.z * svv[k].z + xv.w * svv[k].w;
            }
            float dist = xn2[n] + sn2 - 2.f * dot;
            float rb   = __expf(-dist);

            float qv = __cosf(0.5f * xv0.x + B0) * __cosf(0.5f * xv0.y + B1)
                     * __cosf(0.5f * xv0.z + B2) * __cosf(0.5f * xv0.w + B3);
            qv = fabsf(qv);

            const int row = n0 + n;
            out_rbf[(size_t)row * S_SUP + s] = rb;
            out_qk [(size_t)row * S_SUP + s] = qv;
        }
    }
}

// ---------------------------------------------------------------------------
extern "C" void kernel_launch(void* const* d_in, const int* in_sizes, int n_in,
                              void* d_out, int out_size, void* d_ws, size_t ws_size,
                              hipStream_t stream)
{
    const float* x   = (const float*)d_in[0];
    const float* sv  = (const float*)d_in[1];
    const float* Wf  = (const float*)d_in[2];
    const float* bf  = (const float*)d_in[3];
    const float* Wi  = (const float*)d_in[4];
    const float* bi  = (const float*)d_in[5];
    const float* Wu  = (const float*)d_in[6];
    const float* bu  = (const float*)d_in[7];
    const float* Wo  = (const float*)d_in[8];
    const float* bo  = (const float*)d_in[9];
    const float* pf  = (const float*)d_in[10];
    const float* pi  = (const float*)d_in[11];
    const float* pu  = (const float*)d_in[12];
    const float* po  = (const float*)d_in[13];
    const float* qkp = (const float*)d_in[14];

    float* out     = (float*)d_out;
    float* out_h   = out;
    float* out_rbf = out + OUT_H_SZ;
    float* out_qk  = out + OUT_H_SZ + OUT_RBF_SZ;

    const size_t pre_bytes = (size_t)NROW * 16 * sizeof(float);   // 512 KB
    const bool use_pre = (ws_size >= pre_bytes);
    float* pre = (float*)d_ws;

    if (use_pre) {
        pre_kernel<<<NROW / 16, 256, 0, stream>>>(x, Wf, bf, Wi, bi, Wu, bu, Wo, bo,
                                                  pf, pi, pu, po, pre);
        fused_kernel<true><<<1 + 512, 256, 0, stream>>>(
            x, sv, Wf, bf, Wi, bi, Wu, bu, Wo, bo, pf, pi, pu, po, qkp, pre,
            out_h, out_rbf, out_qk);
    } else {
        fused_kernel<false><<<1 + 512, 256, 0, stream>>>(
            x, sv, Wf, bf, Wi, bi, Wu, bu, Wo, bo, pf, pi, pu, po, qkp, (const float*)nullptr,
            out_h, out_rbf, out_qk);
    }
}

// Round 3
// 149.810 us; speedup vs baseline: 1.1277x; 1.0110x over previous
//
#include <hip/hip_runtime.h>

// Problem constants
#define T_STEPS 128
#define BATCH   64
#define DIMX    32
#define S_SUP   1024
#define NROW    8192          // T*B
#define OUT_H_SZ   (T_STEPS*BATCH*4)      // 32768
#define OUT_RBF_SZ (NROW*S_SUP)           // 8388608

__device__ __forceinline__ float rcp_fast(float x) { return __builtin_amdgcn_rcpf(x); }

// Intra-quad broadcast via DPP quad_perm (VALU latency, vs ~120 cy ds_bpermute)
template<int K>
__device__ __forceinline__ float quad_bcast(float v) {
    constexpr int ctrl = K * 0x55;   // K | K<<2 | K<<4 | K<<6
    return __builtin_bit_cast(float,
        __builtin_amdgcn_mov_dpp(__builtin_bit_cast(int, v), ctrl, 0xF, 0xF, true));
}

// ---------------------------------------------------------------------------
// Kernel 1: pre[row][g][w] = b_g[w] + p_g[w] + sum_d x[row][d] * W_g[w][d]
// row = t*64+b; float4 index = t*256 + b*4 + g
// ---------------------------------------------------------------------------
__global__ __launch_bounds__(256) void pre_kernel(
    const float* __restrict__ x,
    const float* __restrict__ Wf, const float* __restrict__ bf,
    const float* __restrict__ Wi, const float* __restrict__ bi,
    const float* __restrict__ Wu, const float* __restrict__ bu,
    const float* __restrict__ Wo, const float* __restrict__ bo,
    const float* __restrict__ pf, const float* __restrict__ pi,
    const float* __restrict__ pu, const float* __restrict__ po,
    float* __restrict__ pre)
{
    const int tid = threadIdx.x;
    const int rl  = tid >> 4;          // 16 rows per block
    const int gw  = tid & 15;
    const int g   = gw >> 2, w = gw & 3;
    const int row = blockIdx.x * 16 + rl;

    __shared__ float xs[16 * DIMX];
    if (tid < 128) {
        ((float4*)xs)[tid] = ((const float4*)(x + (size_t)blockIdx.x * 16 * DIMX))[tid];
    }
    __syncthreads();

    const float* W  = (g == 0) ? Wf : (g == 1) ? Wi : (g == 2) ? Wu : Wo;
    const float* bb = (g == 0) ? bf : (g == 1) ? bi : (g == 2) ? bu : bo;
    const float* pp = (g == 0) ? pf : (g == 1) ? pi : (g == 2) ? pu : po;

    float acc = bb[w] + pp[w];
    const float* Wr = W + w * 36;      // row stride D+H = 36
    const float* xr = xs + rl * DIMX;
#pragma unroll
    for (int d = 0; d < DIMX; d++) acc += xr[d] * Wr[d];

    pre[(row * 4 + g) * 4 + w] = acc;
}

// ---------------------------------------------------------------------------
// Kernel 2 (fused): block 0 = sequential LSTM, blocks 1..512 = rbf+qk tiles
// ---------------------------------------------------------------------------
template <bool USE_PRE>
__global__ __launch_bounds__(256) void fused_kernel(
    const float* __restrict__ x,  const float* __restrict__ sv,
    const float* __restrict__ Wf, const float* __restrict__ bf,
    const float* __restrict__ Wi, const float* __restrict__ bi,
    const float* __restrict__ Wu, const float* __restrict__ bu,
    const float* __restrict__ Wo, const float* __restrict__ bo,
    const float* __restrict__ pf, const float* __restrict__ pi,
    const float* __restrict__ pu, const float* __restrict__ po,
    const float* __restrict__ qkp, const float* __restrict__ pre,
    float* __restrict__ out_h, float* __restrict__ out_rbf, float* __restrict__ out_qk)
{
    __shared__ float xs[BATCH * DIMX];   // rbf path: 64-row x tile (8 KB)
    __shared__ float xn2[BATCH];
    const int tid = threadIdx.x;

    if (blockIdx.x == 0) {
        // ================= LSTM: thread = (b, g); 4 wires in-lane ==========
        const int b = tid >> 2, g = tid & 3;
        const float* W = (g == 0) ? Wf : (g == 1) ? Wi : (g == 2) ? Wu : Wo;

        float Wh[4][4];                      // hidden part W[w][32+j]
#pragma unroll
        for (int w = 0; w < 4; w++)
#pragma unroll
            for (int j = 0; j < 4; j++) Wh[w][j] = W[w * 36 + 32 + j];

        // per-lane activation constants: g==2 -> tanh = 2*sigmoid(2x)-1
        const float kexp = (g == 2) ? -2.f : -1.f;
        const float Aa   = (g == 2) ?  2.f :  1.f;
        const float Bb   = (g == 2) ? -1.f :  0.f;

        float h0 = 0.f, h1 = 0.f, h2 = 0.f, h3 = 0.f;
        float c0 = 0.f, c1 = 0.f, c2 = 0.f, c3 = 0.f;
        const int base = b * 4 + g;          // float4 index inside one t slab (256/t)
        const float4* prep = (const float4*)pre;

        float  bbp[4];
        float4 Wxv[4][8];                    // fallback path only
        if constexpr (!USE_PRE) {
            const float* bptr = (g == 0) ? bf : (g == 1) ? bi : (g == 2) ? bu : bo;
            const float* pptr = (g == 0) ? pf : (g == 1) ? pi : (g == 2) ? pu : po;
#pragma unroll
            for (int w = 0; w < 4; w++) {
                bbp[w] = bptr[w] + pptr[w];
#pragma unroll
                for (int k = 0; k < 8; k++) Wxv[w][k] = ((const float4*)(W + w * 36))[k];
            }
        }

        // One LSTM step; consumes bufv (named register), immediately issues
        // the prefetch for step t+8 into the same named register -> 8 loads
        // in flight, no dynamic register indexing (stays in VGPRs).
        auto lstm_step = [&](int t, float4& bufv) {
            float a0, a1, a2, a3;
            if constexpr (USE_PRE) {
                a0 = bufv.x; a1 = bufv.y; a2 = bufv.z; a3 = bufv.w;
                int tn = t + 8;
                if (tn < T_STEPS) bufv = prep[base + tn * 256];
            } else {
                const float4* xr = (const float4*)(x + (size_t)(t * BATCH + b) * DIMX);
                float4 xv[8];
#pragma unroll
                for (int k = 0; k < 8; k++) xv[k] = xr[k];
                a0 = bbp[0]; a1 = bbp[1]; a2 = bbp[2]; a3 = bbp[3];
#pragma unroll
                for (int k = 0; k < 8; k++) {
                    a0 += xv[k].x * Wxv[0][k].x + xv[k].y * Wxv[0][k].y + xv[k].z * Wxv[0][k].z + xv[k].w * Wxv[0][k].w;
                    a1 += xv[k].x * Wxv[1][k].x + xv[k].y * Wxv[1][k].y + xv[k].z * Wxv[1][k].z + xv[k].w * Wxv[1][k].w;
                    a2 += xv[k].x * Wxv[2][k].x + xv[k].y * Wxv[2][k].y + xv[k].z * Wxv[2][k].z + xv[k].w * Wxv[2][k].w;
                    a3 += xv[k].x * Wxv[3][k].x + xv[k].y * Wxv[3][k].y + xv[k].z * Wxv[3][k].z + xv[k].w * Wxv[3][k].w;
                }
            }
            // hidden contribution
            a0 += h0 * Wh[0][0] + h1 * Wh[0][1] + h2 * Wh[0][2] + h3 * Wh[0][3];
            a1 += h0 * Wh[1][0] + h1 * Wh[1][1] + h2 * Wh[1][2] + h3 * Wh[1][3];
            a2 += h0 * Wh[2][0] + h1 * Wh[2][1] + h2 * Wh[2][2] + h3 * Wh[2][3];
            a3 += h0 * Wh[3][0] + h1 * Wh[3][1] + h2 * Wh[3][2] + h3 * Wh[3][3];

            // closed-form circuit: C_w = cos(angle_w); PERM_WRAP-conjugated Z
            float C0 = __cosf(a0), C1 = __cosf(a1), C2 = __cosf(a2), C3 = __cosf(a3);
            float t23 = C2 * C3;
            float m01 = C0 * C1;
            float r0 = C1 * t23;     // <Z0> = C1 C2 C3
            float r1 = m01;          // <Z1> = C0 C1
            float r2 = m01 * C2;     // <Z2> = C0 C1 C2
            float r3 = m01 * t23;    // <Z3> = C0 C1 C2 C3

            // activation (sigmoid, or tanh for g==2), branch-free per-lane consts
            float o0 = Aa * rcp_fast(1.f + __expf(r0 * kexp)) + Bb;
            float o1 = Aa * rcp_fast(1.f + __expf(r1 * kexp)) + Bb;
            float o2 = Aa * rcp_fast(1.f + __expf(r2 * kexp)) + Bb;
            float o3 = Aa * rcp_fast(1.f + __expf(r3 * kexp)) + Bb;

            // gather f/i/u/o vectors from quad lanes (g = 0,1,2,3) via DPP
            float f0 = quad_bcast<0>(o0), f1 = quad_bcast<0>(o1), f2 = quad_bcast<0>(o2), f3 = quad_bcast<0>(o3);
            float i0 = quad_bcast<1>(o0), i1 = quad_bcast<1>(o1), i2 = quad_bcast<1>(o2), i3 = quad_bcast<1>(o3);
            float u0 = quad_bcast<2>(o0), u1 = quad_bcast<2>(o1), u2 = quad_bcast<2>(o2), u3 = quad_bcast<2>(o3);
            float z0 = quad_bcast<3>(o0), z1 = quad_bcast<3>(o1), z2 = quad_bcast<3>(o2), z3 = quad_bcast<3>(o3);

            c0 = f0 * c0 + i0 * u0;
            c1 = f1 * c1 + i1 * u1;
            c2 = f2 * c2 + i2 * u2;
            c3 = f3 * c3 + i3 * u3;

            float t0 = 2.f * rcp_fast(1.f + __expf(-2.f * c0)) - 1.f;
            float t1 = 2.f * rcp_fast(1.f + __expf(-2.f * c1)) - 1.f;
            float t2 = 2.f * rcp_fast(1.f + __expf(-2.f * c2)) - 1.f;
            float t3 = 2.f * rcp_fast(1.f + __expf(-2.f * c3)) - 1.f;
            h0 = z0 * t0; h1 = z1 * t1; h2 = z2 * t2; h3 = z3 * t3;

            if (g == 0) {
                float4 hv; hv.x = h0; hv.y = h1; hv.z = h2; hv.w = h3;
                ((float4*)out_h)[t * BATCH + b] = hv;
            }
        };

        // 8 NAMED prefetch registers (no array -> cannot be demoted to scratch)
        float4 pb0, pb1, pb2, pb3, pb4, pb5, pb6, pb7;
        if constexpr (USE_PRE) {
            pb0 = prep[base];           pb1 = prep[base + 256];
            pb2 = prep[base + 512];     pb3 = prep[base + 768];
            pb4 = prep[base + 1024];    pb5 = prep[base + 1280];
            pb6 = prep[base + 1536];    pb7 = prep[base + 1792];
        }
#pragma unroll 1
        for (int tt = 0; tt < T_STEPS; tt += 8) {
            lstm_step(tt + 0, pb0);
            lstm_step(tt + 1, pb1);
            lstm_step(tt + 2, pb2);
            lstm_step(tt + 3, pb3);
            lstm_step(tt + 4, pb4);
            lstm_step(tt + 5, pb5);
            lstm_step(tt + 6, pb6);
            lstm_step(tt + 7, pb7);
        }
    } else {
        // ================= rbf + qk tile: 64 n x 256 s =====================
        const int bid = blockIdx.x - 1;
        const int n0  = (bid >> 2) * BATCH;
        const int s0  = (bid & 3) * 256;

        float4* xs4 = (float4*)xs;
        const float4* xg = (const float4*)(x + (size_t)n0 * DIMX);
        float4 t0v = xg[tid];
        float4 t1v = xg[tid + 256];
        xs4[tid]       = t0v;
        xs4[tid + 256] = t1v;

        // per-row |x|^2 from staging registers: 8 lanes per row, xor-reduce.
        // (replaces the old stride-32 LDS reads = 64-way bank conflict)
        float p0 = t0v.x * t0v.x + t0v.y * t0v.y + t0v.z * t0v.z + t0v.w * t0v.w;
        float p1 = t1v.x * t1v.x + t1v.y * t1v.y + t1v.z * t1v.z + t1v.w * t1v.w;
        p0 += __shfl_xor(p0, 1); p1 += __shfl_xor(p1, 1);
        p0 += __shfl_xor(p0, 2); p1 += __shfl_xor(p1, 2);
        p0 += __shfl_xor(p0, 4); p1 += __shfl_xor(p1, 4);
        if ((tid & 7) == 0) {
            xn2[tid >> 3]        = p0;   // rows 0..31
            xn2[(tid >> 3) + 32] = p1;   // rows 32..63
        }

        const int s = s0 + tid;              // this thread's support vector
        float4 svv[8];
        const float4* svg = (const float4*)(sv + (size_t)s * DIMX);
#pragma unroll
        for (int k = 0; k < 8; k++) svv[k] = svg[k];
        float sn2 = 0.f;
#pragma unroll
        for (int k = 0; k < 8; k++)
            sn2 += svv[k].x * svv[k].x + svv[k].y * svv[k].y + svv[k].z * svv[k].z + svv[k].w * svv[k].w;

        // qk s-side: B_w = sv_w/2 + qk_w   (PERM_LINE drops out of sx@sy.T)
        const float B0 = 0.5f * svv[0].x + qkp[0];
        const float B1 = 0.5f * svv[0].y + qkp[1];
        const float B2 = 0.5f * svv[0].z + qkp[2];
        const float B3 = 0.5f * svv[0].w + qkp[3];
        __syncthreads();

#pragma unroll 4
        for (int n = 0; n < BATCH; n++) {
            const float4* xr4 = (const float4*)(xs + n * DIMX);   // broadcast reads
            float4 xv0 = xr4[0];
            float dot = xv0.x * svv[0].x + xv0.y * svv[0].y + xv0.z * svv[0].z + xv0.w * svv[0].w;
#pragma unroll
            for (int k = 1; k < 8; k++) {
                float4 xv = xr4[k];
                dot += xv.x * svv[k].x + xv.y * svv[k].y + xv.z * svv[k].z + xv.w * svv[k].w;
            }
            float dist = xn2[n] + sn2 - 2.f * dot;
            float rb   = __expf(-dist);

            float qv = __cosf(0.5f * xv0.x + B0) * __cosf(0.5f * xv0.y + B1)
                     * __cosf(0.5f * xv0.z + B2) * __cosf(0.5f * xv0.w + B3);
            qv = fabsf(qv);

            const int row = n0 + n;
            out_rbf[(size_t)row * S_SUP + s] = rb;
            out_qk [(size_t)row * S_SUP + s] = qv;
        }
    }
}

// ---------------------------------------------------------------------------
extern "C" void kernel_launch(void* const* d_in, const int* in_sizes, int n_in,
                              void* d_out, int out_size, void* d_ws, size_t ws_size,
                              hipStream_t stream)
{
    const float* x   = (const float*)d_in[0];
    const float* sv  = (const float*)d_in[1];
    const float* Wf  = (const float*)d_in[2];
    const float* bf  = (const float*)d_in[3];
    const float* Wi  = (const float*)d_in[4];
    const float* bi  = (const float*)d_in[5];
    const float* Wu  = (const float*)d_in[6];
    const float* bu  = (const float*)d_in[7];
    const float* Wo  = (const float*)d_in[8];
    const float* bo  = (const float*)d_in[9];
    const float* pf  = (const float*)d_in[10];
    const float* pi  = (const float*)d_in[11];
    const float* pu  = (const float*)d_in[12];
    const float* po  = (const float*)d_in[13];
    const float* qkp = (const float*)d_in[14];

    float* out     = (float*)d_out;
    float* out_h   = out;
    float* out_rbf = out + OUT_H_SZ;
    float* out_qk  = out + OUT_H_SZ + OUT_RBF_SZ;

    const size_t pre_bytes = (size_t)NROW * 16 * sizeof(float);   // 512 KB
    const bool use_pre = (ws_size >= pre_bytes);
    float* pre = (float*)d_ws;

    if (use_pre) {
        pre_kernel<<<NROW / 16, 256, 0, stream>>>(x, Wf, bf, Wi, bi, Wu, bu, Wo, bo,
                                                  pf, pi, pu, po, pre);
        fused_kernel<true><<<1 + 512, 256, 0, stream>>>(
            x, sv, Wf, bf, Wi, bi, Wu, bu, Wo, bo, pf, pi, pu, po, qkp, pre,
            out_h, out_rbf, out_qk);
    } else {
        fused_kernel<false><<<1 + 512, 256, 0, stream>>>(
            x, sv, Wf, bf, Wi, bi, Wu, bu, Wo, bo, pf, pi, pu, po, qkp, (const float*)nullptr,
            out_h, out_rbf, out_qk);
    }
}

// Round 4
// 149.436 us; speedup vs baseline: 1.1305x; 1.0025x over previous
//
#include <hip/hip_runtime.h>

// Problem constants
#define T_STEPS 128
#define BATCH   64
#define DIMX    32
#define S_SUP   1024
#define NROW    8192          // T*B
#define OUT_H_SZ   (T_STEPS*BATCH*4)      // 32768
#define OUT_RBF_SZ (NROW*S_SUP)           // 8388608

__device__ __forceinline__ float rcp_fast(float x) { return __builtin_amdgcn_rcpf(x); }

// Intra-quad broadcast via DPP quad_perm (VALU latency, vs ~120 cy ds_bpermute)
template<int K>
__device__ __forceinline__ float quad_bcast(float v) {
    constexpr int ctrl = K * 0x55;   // K | K<<2 | K<<4 | K<<6
    return __builtin_bit_cast(float,
        __builtin_amdgcn_mov_dpp(__builtin_bit_cast(int, v), ctrl, 0xF, 0xF, true));
}

// ---------------------------------------------------------------------------
// Kernel 1: pre[row][g][w] = b_g[w] + p_g[w] + sum_d x[row][d] * W_g[w][d]
// row = t*64+b; float4 index = t*256 + b*4 + g
// ---------------------------------------------------------------------------
__global__ __launch_bounds__(256) void pre_kernel(
    const float* __restrict__ x,
    const float* __restrict__ Wf, const float* __restrict__ bf,
    const float* __restrict__ Wi, const float* __restrict__ bi,
    const float* __restrict__ Wu, const float* __restrict__ bu,
    const float* __restrict__ Wo, const float* __restrict__ bo,
    const float* __restrict__ pf, const float* __restrict__ pi,
    const float* __restrict__ pu, const float* __restrict__ po,
    float* __restrict__ pre)
{
    const int tid = threadIdx.x;
    const int rl  = tid >> 4;          // 16 rows per block
    const int gw  = tid & 15;
    const int g   = gw >> 2, w = gw & 3;
    const int row = blockIdx.x * 16 + rl;

    __shared__ float xs[16 * DIMX];
    if (tid < 128) {
        ((float4*)xs)[tid] = ((const float4*)(x + (size_t)blockIdx.x * 16 * DIMX))[tid];
    }
    __syncthreads();

    const float* W  = (g == 0) ? Wf : (g == 1) ? Wi : (g == 2) ? Wu : Wo;
    const float* bb = (g == 0) ? bf : (g == 1) ? bi : (g == 2) ? bu : bo;
    const float* pp = (g == 0) ? pf : (g == 1) ? pi : (g == 2) ? pu : po;

    float acc = bb[w] + pp[w];
    const float* Wr = W + w * 36;      // row stride D+H = 36
    const float* xr = xs + rl * DIMX;
#pragma unroll
    for (int d = 0; d < DIMX; d++) acc += xr[d] * Wr[d];

    pre[(row * 4 + g) * 4 + w] = acc;
}

// ---------------------------------------------------------------------------
// Kernel 2 (fused): block 0 = sequential LSTM, blocks 1..512 = rbf+qk tiles
// ---------------------------------------------------------------------------
__global__ __launch_bounds__(256) void fused_kernel(
    const float* __restrict__ x,  const float* __restrict__ sv,
    const float* __restrict__ Wf, const float* __restrict__ bf,
    const float* __restrict__ Wi, const float* __restrict__ bi,
    const float* __restrict__ Wu, const float* __restrict__ bu,
    const float* __restrict__ Wo, const float* __restrict__ bo,
    const float* __restrict__ pf, const float* __restrict__ pi,
    const float* __restrict__ pu, const float* __restrict__ po,
    const float* __restrict__ qkp, const float* __restrict__ pre,
    float* __restrict__ out_h, float* __restrict__ out_rbf, float* __restrict__ out_qk)
{
    __shared__ float xs[BATCH * DIMX];   // rbf path: 64-row x tile (8 KB)
    __shared__ float xn2[BATCH];
    const int tid = threadIdx.x;

    if (blockIdx.x == 0) {
        // ================= LSTM: thread = (b, g); 4 wires in-lane ==========
        __builtin_amdgcn_s_setprio(3);   // win issue arbitration vs rbf waves
        const int b = tid >> 2, g = tid & 3;
        const float* W = (g == 0) ? Wf : (g == 1) ? Wi : (g == 2) ? Wu : Wo;

        float Wh[4][4];                      // hidden part W[w][32+j]
#pragma unroll
        for (int w = 0; w < 4; w++)
#pragma unroll
            for (int j = 0; j < 4; j++) Wh[w][j] = W[w * 36 + 32 + j];

        // per-lane activation constants: g==2 -> tanh = 2*sigmoid(2x)-1
        const float kexp = (g == 2) ? -2.f : -1.f;
        const float Aa   = (g == 2) ?  2.f :  1.f;
        const float Bb   = (g == 2) ? -1.f :  0.f;
        const bool  isg1 = (g == 1), isg2 = (g == 2), isg3 = (g == 3);

        float h0 = 0.f, h1 = 0.f, h2 = 0.f, h3 = 0.f;
        float c0 = 0.f, c1 = 0.f, c2 = 0.f, c3 = 0.f;
        const int base = b * 4 + g;          // float4 index inside one t slab (256/t)
        const float4* prep = (const float4*)pre;

        // One LSTM step on an already-loaded float4 (no loads, no branches).
        auto lstm_step = [&](int t, float4 cur) {
            float a0 = cur.x, a1 = cur.y, a2 = cur.z, a3 = cur.w;
            // hidden contribution
            a0 += h0 * Wh[0][0] + h1 * Wh[0][1] + h2 * Wh[0][2] + h3 * Wh[0][3];
            a1 += h0 * Wh[1][0] + h1 * Wh[1][1] + h2 * Wh[1][2] + h3 * Wh[1][3];
            a2 += h0 * Wh[2][0] + h1 * Wh[2][1] + h2 * Wh[2][2] + h3 * Wh[2][3];
            a3 += h0 * Wh[3][0] + h1 * Wh[3][1] + h2 * Wh[3][2] + h3 * Wh[3][3];

            // closed-form circuit: C_w = cos(angle_w); PERM_WRAP-conjugated Z
            float C0 = __cosf(a0), C1 = __cosf(a1), C2 = __cosf(a2), C3 = __cosf(a3);
            float t23 = C2 * C3;
            float m01 = C0 * C1;
            float r0 = C1 * t23;     // <Z0> = C1 C2 C3
            float r1 = m01;          // <Z1> = C0 C1
            float r2 = m01 * C2;     // <Z2> = C0 C1 C2
            float r3 = m01 * t23;    // <Z3> = C0 C1 C2 C3

            // activation (sigmoid, or tanh for g==2), branch-free per-lane consts
            float o0 = Aa * rcp_fast(1.f + __expf(r0 * kexp)) + Bb;
            float o1 = Aa * rcp_fast(1.f + __expf(r1 * kexp)) + Bb;
            float o2 = Aa * rcp_fast(1.f + __expf(r2 * kexp)) + Bb;
            float o3 = Aa * rcp_fast(1.f + __expf(r3 * kexp)) + Bb;

            // gather f/i/u/o vectors from quad lanes (g = 0,1,2,3) via DPP
            float f0 = quad_bcast<0>(o0), f1 = quad_bcast<0>(o1), f2 = quad_bcast<0>(o2), f3 = quad_bcast<0>(o3);
            float i0 = quad_bcast<1>(o0), i1 = quad_bcast<1>(o1), i2 = quad_bcast<1>(o2), i3 = quad_bcast<1>(o3);
            float u0 = quad_bcast<2>(o0), u1 = quad_bcast<2>(o1), u2 = quad_bcast<2>(o2), u3 = quad_bcast<2>(o3);
            float z0 = quad_bcast<3>(o0), z1 = quad_bcast<3>(o1), z2 = quad_bcast<3>(o2), z3 = quad_bcast<3>(o3);

            c0 = f0 * c0 + i0 * u0;
            c1 = f1 * c1 + i1 * u1;
            c2 = f2 * c2 + i2 * u2;
            c3 = f3 * c3 + i3 * u3;

            float t0 = 2.f * rcp_fast(1.f + __expf(-2.f * c0)) - 1.f;
            float t1 = 2.f * rcp_fast(1.f + __expf(-2.f * c1)) - 1.f;
            float t2 = 2.f * rcp_fast(1.f + __expf(-2.f * c2)) - 1.f;
            float t3 = 2.f * rcp_fast(1.f + __expf(-2.f * c3)) - 1.f;
            h0 = z0 * t0; h1 = z1 * t1; h2 = z2 * t2; h3 = z3 * t3;

            // h is quad-uniform: lane (b,g) stores component g -> every lane
            // stores (coalesced, UNCONDITIONAL -> static vmcnt tracking)
            float hsel = isg1 ? h1 : h0;
            hsel = isg2 ? h2 : hsel;
            hsel = isg3 ? h3 : hsel;
            out_h[t * 256 + tid] = hsel;
        };

        // Chunked double-buffer: 8 cur + 8 nxt NAMED registers. All loads are
        // unconditional (last chunk clamps to re-read rows 120..127, unused),
        // issued a full chunk (~>1200 cy) before their consume.
        float4 cb0, cb1, cb2, cb3, cb4, cb5, cb6, cb7;
        cb0 = prep[base];           cb1 = prep[base + 256];
        cb2 = prep[base + 512];     cb3 = prep[base + 768];
        cb4 = prep[base + 1024];    cb5 = prep[base + 1280];
        cb6 = prep[base + 1536];    cb7 = prep[base + 1792];

#pragma unroll 1
        for (int tt = 0; tt < T_STEPS; tt += 8) {
            // issue next-chunk loads (branch-free clamped base)
            int nb = tt + 8; nb = (nb > T_STEPS - 8) ? (T_STEPS - 8) : nb;
            const float4* pc = prep + base + nb * 256;
            float4 nb0 = pc[0];
            float4 nb1 = pc[256];
            float4 nb2 = pc[512];
            float4 nb3 = pc[768];
            float4 nb4 = pc[1024];
            float4 nb5 = pc[1280];
            float4 nb6 = pc[1536];
            float4 nb7 = pc[1792];
            __builtin_amdgcn_sched_barrier(0);  // pin loads ahead of compute

            lstm_step(tt + 0, cb0);
            lstm_step(tt + 1, cb1);
            lstm_step(tt + 2, cb2);
            lstm_step(tt + 3, cb3);
            lstm_step(tt + 4, cb4);
            lstm_step(tt + 5, cb5);
            lstm_step(tt + 6, cb6);
            lstm_step(tt + 7, cb7);

            cb0 = nb0; cb1 = nb1; cb2 = nb2; cb3 = nb3;
            cb4 = nb4; cb5 = nb5; cb6 = nb6; cb7 = nb7;
        }
    } else {
        // ================= rbf + qk tile: 64 n x 256 s =====================
        const int bid = blockIdx.x - 1;
        const int n0  = (bid >> 2) * BATCH;
        const int s0  = (bid & 3) * 256;

        float4* xs4 = (float4*)xs;
        const float4* xg = (const float4*)(x + (size_t)n0 * DIMX);
        float4 t0v = xg[tid];
        float4 t1v = xg[tid + 256];
        xs4[tid]       = t0v;
        xs4[tid + 256] = t1v;

        // per-row |x|^2 from staging registers: 8 lanes per row, xor-reduce
        float p0 = t0v.x * t0v.x + t0v.y * t0v.y + t0v.z * t0v.z + t0v.w * t0v.w;
        float p1 = t1v.x * t1v.x + t1v.y * t1v.y + t1v.z * t1v.z + t1v.w * t1v.w;
        p0 += __shfl_xor(p0, 1); p1 += __shfl_xor(p1, 1);
        p0 += __shfl_xor(p0, 2); p1 += __shfl_xor(p1, 2);
        p0 += __shfl_xor(p0, 4); p1 += __shfl_xor(p1, 4);
        if ((tid & 7) == 0) {
            xn2[tid >> 3]        = p0;   // rows 0..31
            xn2[(tid >> 3) + 32] = p1;   // rows 32..63
        }

        const int s = s0 + tid;              // this thread's support vector
        float4 svv[8];
        const float4* svg = (const float4*)(sv + (size_t)s * DIMX);
#pragma unroll
        for (int k = 0; k < 8; k++) svv[k] = svg[k];
        float sn2 = 0.f;
#pragma unroll
        for (int k = 0; k < 8; k++)
            sn2 += svv[k].x * svv[k].x + svv[k].y * svv[k].y + svv[k].z * svv[k].z + svv[k].w * svv[k].w;

        // qk s-side: B_w = sv_w/2 + qk_w   (PERM_LINE drops out of sx@sy.T)
        const float B0 = 0.5f * svv[0].x + qkp[0];
        const float B1 = 0.5f * svv[0].y + qkp[1];
        const float B2 = 0.5f * svv[0].z + qkp[2];
        const float B3 = 0.5f * svv[0].w + qkp[3];
        __syncthreads();

#pragma unroll 4
        for (int n = 0; n < BATCH; n++) {
            const float4* xr4 = (const float4*)(xs + n * DIMX);   // broadcast reads
            float4 xv0 = xr4[0];
            float dot = xv0.x * svv[0].x + xv0.y * svv[0].y + xv0.z * svv[0].z + xv0.w * svv[0].w;
#pragma unroll
            for (int k = 1; k < 8; k++) {
                float4 xv = xr4[k];
                dot += xv.x * svv[k].x + xv.y * svv[k].y + xv.z * svv[k].z + xv.w * svv[k].w;
            }
            float dist = xn2[n] + sn2 - 2.f * dot;
            float rb   = __expf(-dist);

            float qv = __cosf(0.5f * xv0.x + B0) * __cosf(0.5f * xv0.y + B1)
                     * __cosf(0.5f * xv0.z + B2) * __cosf(0.5f * xv0.w + B3);
            qv = fabsf(qv);

            const int row = n0 + n;
            out_rbf[(size_t)row * S_SUP + s] = rb;
            out_qk [(size_t)row * S_SUP + s] = qv;
        }
    }
}

// ---------------------------------------------------------------------------
extern "C" void kernel_launch(void* const* d_in, const int* in_sizes, int n_in,
                              void* d_out, int out_size, void* d_ws, size_t ws_size,
                              hipStream_t stream)
{
    const float* x   = (const float*)d_in[0];
    const float* sv  = (const float*)d_in[1];
    const float* Wf  = (const float*)d_in[2];
    const float* bf  = (const float*)d_in[3];
    const float* Wi  = (const float*)d_in[4];
    const float* bi  = (const float*)d_in[5];
    const float* Wu  = (const float*)d_in[6];
    const float* bu  = (const float*)d_in[7];
    const float* Wo  = (const float*)d_in[8];
    const float* bo  = (const float*)d_in[9];
    const float* pf  = (const float*)d_in[10];
    const float* pi  = (const float*)d_in[11];
    const float* pu  = (const float*)d_in[12];
    const float* po  = (const float*)d_in[13];
    const float* qkp = (const float*)d_in[14];

    float* out     = (float*)d_out;
    float* out_h   = out;
    float* out_rbf = out + OUT_H_SZ;
    float* out_qk  = out + OUT_H_SZ + OUT_RBF_SZ;

    float* pre = (float*)d_ws;   // 512 KB scratch (NROW*16 floats)

    pre_kernel<<<NROW / 16, 256, 0, stream>>>(x, Wf, bf, Wi, bi, Wu, bu, Wo, bo,
                                              pf, pi, pu, po, pre);
    fused_kernel<<<1 + 512, 256, 0, stream>>>(
        x, sv, Wf, bf, Wi, bi, Wu, bu, Wo, bo, pf, pi, pu, po, qkp, pre,
        out_h, out_rbf, out_qk);
}